// Round 4
// baseline (316.596 us; speedup 1.0000x reference)
//
#include <hip/hip_runtime.h>
#include <stdint.h>

#define M_DIM 16384
#define N_DIM 4096
#define K_DIM 512

#define BM 128
#define BN 256
#define BK 64

typedef int v8i __attribute__((ext_vector_type(8)));
typedef float f32x16 __attribute__((ext_vector_type(16)));

typedef __attribute__((address_space(3))) uint32_t lds_u32_t;
typedef const __attribute__((address_space(1))) uint32_t glob_u32_t;

__device__ __forceinline__ void gload16(const void* g, void* l) {
    __builtin_amdgcn_global_load_lds((glob_u32_t*)g, (lds_u32_t*)l, 16, 0, 0);
}

// one wave per row: fp32 row -> fp8 e4m3 row (8 B/lane) + fp32 sum of squares.
__global__ __launch_bounds__(256)
void convert_norm_kernel(const float* __restrict__ X, const float* __restrict__ C,
                         uint8_t* __restrict__ Xf8, uint8_t* __restrict__ Cf8,
                         float* __restrict__ xsq, float* __restrict__ csq) {
    const int wave = threadIdx.x >> 6;
    const int lane = threadIdx.x & 63;
    const int row = blockIdx.x * 4 + wave;
    const float* src;
    uint8_t* dst;
    float* nrm;
    int r;
    if (row < M_DIM) { src = X; dst = Xf8; nrm = xsq; r = row; }
    else             { src = C; dst = Cf8; nrm = csq; r = row - M_DIM; }

    const float4* p = (const float4*)(src + (size_t)r * K_DIM) + lane * 2;
    float4 a = p[0], b = p[1];
    uint32_t lo = 0, hi = 0;
    lo = __builtin_amdgcn_cvt_pk_fp8_f32(a.x, a.y, lo, false);
    lo = __builtin_amdgcn_cvt_pk_fp8_f32(a.z, a.w, lo, true);
    hi = __builtin_amdgcn_cvt_pk_fp8_f32(b.x, b.y, hi, false);
    hi = __builtin_amdgcn_cvt_pk_fp8_f32(b.z, b.w, hi, true);
    *(uint2*)(dst + (size_t)r * K_DIM + lane * 8) = make_uint2(lo, hi);

    float s = a.x*a.x + a.y*a.y + a.z*a.z + a.w*a.w
            + b.x*b.x + b.y*b.y + b.z*b.z + b.w*b.w;
    #pragma unroll
    for (int off = 32; off > 0; off >>= 1) s += __shfl_down(s, off, 64);
    if (lane == 0) nrm[r] = s;
}

// Block 128x256, 4 waves 2x2, wave tile 64x128 = 2x4 of mfma_scale 32x32x64 fp8.
// BK=64, double-buffered LDS (2 x 24 KB): issue next slab's global_load_lds right
// after the barrier, consume current buffer behind it -> staging hides under MFMA.
// LDS rows are 64 B (4 chunks), chunk c of row r at slot (c+r)&3 -> conflict-free
// ds_read_b128 AND realizable by global_load_lds (lane-contiguous LDS, per-lane
// global address freedom). k-chunk mapping is permutation-invariant (same map on
// A and B).
// B columns are interleaved: panel p row r <- global col bn + (p>>2)*128 + 4r + (p&3),
// so lane r31 of every j-tile owns 4 consecutive output cols -> float4 stores.
__global__ __launch_bounds__(256, 2)
void rbf_mfma_kernel(const uint8_t* __restrict__ A8, const uint8_t* __restrict__ B8,
                     const float* __restrict__ xsq, const float* __restrict__ csq,
                     float* __restrict__ out) {
    __shared__ uint8_t As[2 * BM * BK];   // 16 KB
    __shared__ uint8_t Bs[2 * BN * BK];   // 32 KB

    const int tid  = threadIdx.x;
    const int lane = tid & 63;
    const int wave = tid >> 6;
    const int h    = lane >> 5;
    const int r31  = lane & 31;

    const int bn = (blockIdx.x & 15) * BN;   // inner -> A-tile L2 reuse
    const int bm = (blockIdx.x >> 4) * BM;

    const int wm = (wave >> 1) * 64;
    const int wn = (wave & 1) * 128;

    // ---- staging maps ----
    const int tr = tid >> 2;            // 0..63
    const int tc = tid & 3;
    const int cc = (tc - tr) & 3;       // swizzled k-chunk this thread fetches
    const int b7 = tid >> 7;

    const uint8_t* gA0 = A8 + (size_t)(bm + tr) * K_DIM + cc * 16;
    const uint8_t* gA1 = gA0 + (size_t)64 * K_DIM;
    const int brow = 4 * (tr & 31);
    const uint8_t* gB[4];
    #pragma unroll
    for (int R = 0; R < 4; ++R) {
        const int p = 2 * R + b7;
        const int grow = bn + (p >> 2) * 128 + brow + (p & 3);
        gB[R] = B8 + (size_t)grow * K_DIM + cc * 16;
    }

    // ---- prologue: stage slab 0 into buffer 0 ----
    {
        uint8_t* aD = As + wave * 1024;
        uint8_t* bD = Bs + wave * 1024;
        gload16(gA0, aD);
        gload16(gA1, aD + 4096);
        #pragma unroll
        for (int R = 0; R < 4; ++R) gload16(gB[R], bD + R * 4096);
    }
    int koff = 64;

    // ---- fragment-read constants (k-invariant) ----
    const int s0 = ((2 * h + 0 + r31) & 3) * 16;
    const int s1 = ((2 * h + 1 + r31) & 3) * 16;
    const int aOff = (wave >> 1) * 2 * 2048 + r31 * 64;
    const int bOff = (wave & 1) * 4 * 2048 + r31 * 64;

    f32x16 acc[2][4] = {};   // 128 VGPRs

    for (int kk = 0; kk < K_DIM / BK; ++kk) {
        __syncthreads();   // drains slab-kk loads (issued one consume-phase ago)
        if (kk < K_DIM / BK - 1) {
            uint8_t* aD = As + ((kk + 1) & 1) * 8192 + wave * 1024;
            uint8_t* bD = Bs + ((kk + 1) & 1) * 16384 + wave * 1024;
            gload16(gA0 + koff, aD);
            gload16(gA1 + koff, aD + 4096);
            #pragma unroll
            for (int R = 0; R < 4; ++R) gload16(gB[R] + koff, bD + R * 4096);
            koff += 64;
        }
        const uint8_t* aB = As + (kk & 1) * 8192 + aOff;
        const uint8_t* bB = Bs + (kk & 1) * 16384 + bOff;
        v8i av[2], bv[4];
        #pragma unroll
        for (int i = 0; i < 2; ++i) {
            uint4 lo = *(const uint4*)(aB + i * 2048 + s0);
            uint4 hi = *(const uint4*)(aB + i * 2048 + s1);
            av[i] = (v8i){(int)lo.x, (int)lo.y, (int)lo.z, (int)lo.w,
                          (int)hi.x, (int)hi.y, (int)hi.z, (int)hi.w};
        }
        #pragma unroll
        for (int j = 0; j < 4; ++j) {
            uint4 lo = *(const uint4*)(bB + j * 2048 + s0);
            uint4 hi = *(const uint4*)(bB + j * 2048 + s1);
            bv[j] = (v8i){(int)lo.x, (int)lo.y, (int)lo.z, (int)lo.w,
                          (int)hi.x, (int)hi.y, (int)hi.z, (int)hi.w};
        }
        #pragma unroll
        for (int i = 0; i < 2; ++i)
            #pragma unroll
            for (int j = 0; j < 4; ++j)
                acc[i][j] = __builtin_amdgcn_mfma_scale_f32_32x32x64_f8f6f4(
                    av[i], bv[j], acc[i][j],
                    0 /*fp8*/, 0 /*fp8*/,
                    0, 0x7F7F7F7Fu, 0, 0x7F7F7F7Fu);
    }

    // ---- epilogue: out = exp(-(xsq - 2*cross + csq)), float4 stores ----
    // C/D 32x32: tile col = lane&31 -> global col bn + wn + 4*r31 + j (interleave)
    const float4 cs4 = *(const float4*)(csq + bn + wn + 4 * r31);

    #pragma unroll
    for (int i = 0; i < 2; ++i) {
        #pragma unroll
        for (int r = 0; r < 16; ++r) {
            const int gm = bm + wm + 32 * i + 4 * h + (r & 3) + 8 * (r >> 2);
            const float xs = xsq[gm];
            float4 o;
            o.x = __expf(-(xs - 2.0f * acc[i][0][r] + cs4.x));
            o.y = __expf(-(xs - 2.0f * acc[i][1][r] + cs4.y));
            o.z = __expf(-(xs - 2.0f * acc[i][2][r] + cs4.z));
            o.w = __expf(-(xs - 2.0f * acc[i][3][r] + cs4.w));
            *(float4*)(out + (size_t)gm * N_DIM + bn + wn + 4 * r31) = o;
        }
    }
}

extern "C" void kernel_launch(void* const* d_in, const int* in_sizes, int n_in,
                              void* d_out, int out_size, void* d_ws, size_t ws_size,
                              hipStream_t stream) {
    const float* X = (const float*)d_in[0];
    const float* C = (const float*)d_in[1];
    float* out = (float*)d_out;

    uint8_t* Xf8 = (uint8_t*)d_ws;                            // 8 MB
    uint8_t* Cf8 = Xf8 + (size_t)M_DIM * K_DIM;               // 2 MB
    float* xsq = (float*)(Cf8 + (size_t)N_DIM * K_DIM);       // 64 KB
    float* csq = xsq + M_DIM;                                 // 16 KB

    convert_norm_kernel<<<(M_DIM + N_DIM) / 4, 256, 0, stream>>>(X, C, Xf8, Cf8, xsq, csq);
    rbf_mfma_kernel<<<(M_DIM / BM) * (N_DIM / BN), 256, 0, stream>>>(Xf8, Cf8, xsq, csq, out);
}

// Round 5
// 316.527 us; speedup vs baseline: 1.0002x; 1.0002x over previous
//
#include <hip/hip_runtime.h>
#include <stdint.h>

#define M_DIM 16384
#define N_DIM 4096
#define K_DIM 512

#define BM 128
#define BN 256

typedef int v8i __attribute__((ext_vector_type(8)));
typedef float f32x16 __attribute__((ext_vector_type(16)));

// ---------------------------------------------------------------------------
// Fragment-major packed layout (both A and B), chosen so a wave's MFMA operand
// load is a fully-coalesced pair of global_load_dwordx4:
//   byte(panel P, kstep ks, khalf h, lane r, inner b) =
//       (P*8 + ks)*2048 + h*1024 + r*32 + b          (r in [0,32), b in [0,32))
// Lane l of a wave (r=l&31, h=l>>5) reads 32 B at  base + h*1024 + r*32.
// A panels: P = global_row >> 5 (natural row order).
// B panels are COLUMN-INTERLEAVED for the float4 epilogue:
//   global col c -> panel Q = (c>>7)*4 + (c&3), slot r = (c>>2)&31
//   so j-tile j of a block covers cols  bn + wn + 4*r + j.
// k-slot mapping is applied identically to A and B -> dot product aligns.
// ---------------------------------------------------------------------------

// one wave per row: fp32 row -> fp8 e4m3 fragment-packed row + fp32 sum of squares
__global__ __launch_bounds__(256)
void convert_norm_kernel(const float* __restrict__ X, const float* __restrict__ C,
                         uint8_t* __restrict__ Apack, uint8_t* __restrict__ Bpack,
                         float* __restrict__ xsq, float* __restrict__ csq) {
    const int wave = threadIdx.x >> 6;
    const int lane = threadIdx.x & 63;
    const int row = blockIdx.x * 4 + wave;

    const float* src;
    uint8_t* dst;
    float* nrm;
    int r, panel, slot;
    if (row < M_DIM) {
        src = X; dst = Apack; nrm = xsq; r = row;
        panel = r >> 5; slot = r & 31;
    } else {
        src = C; dst = Bpack; nrm = csq; r = row - M_DIM;
        panel = (r >> 7) * 4 + (r & 3); slot = (r >> 2) & 31;
    }

    const float4* p = (const float4*)(src + (size_t)r * K_DIM) + lane * 2;
    float4 a = p[0], b = p[1];
    uint32_t lo = 0, hi = 0;
    lo = __builtin_amdgcn_cvt_pk_fp8_f32(a.x, a.y, lo, false);
    lo = __builtin_amdgcn_cvt_pk_fp8_f32(a.z, a.w, lo, true);
    hi = __builtin_amdgcn_cvt_pk_fp8_f32(b.x, b.y, hi, false);
    hi = __builtin_amdgcn_cvt_pk_fp8_f32(b.z, b.w, hi, true);

    // lane covers k = 8*lane .. 8*lane+8  ->  ks = lane>>3, h = (lane>>2)&1, b = (lane&3)*8
    const size_t off = (size_t)(panel * 8 + (lane >> 3)) * 2048
                     + ((lane >> 2) & 1) * 1024 + slot * 32 + (lane & 3) * 8;
    *(uint2*)(dst + off) = make_uint2(lo, hi);

    float s = a.x*a.x + a.y*a.y + a.z*a.z + a.w*a.w
            + b.x*b.x + b.y*b.y + b.z*b.z + b.w*b.w;
    #pragma unroll
    for (int off2 = 32; off2 > 0; off2 >>= 1) s += __shfl_down(s, off2, 64);
    if (lane == 0) nrm[r] = s;
}

// Block 128x256, 4 waves 2x2, wave tile 64x128 = 2x4 of mfma_scale 32x32x64 fp8.
// NO LDS, NO BARRIERS: operands load straight global(L2)->VGPR from the packed
// buffers; the fully-unrolled K-loop lets the compiler interleave buffer loads
// with MFMA under fine-grained vmcnt (the AITER pattern).
__global__ __launch_bounds__(256, 2)
void rbf_mfma_kernel(const uint8_t* __restrict__ Apack, const uint8_t* __restrict__ Bpack,
                     const float* __restrict__ xsq, const float* __restrict__ csq,
                     float* __restrict__ out) {
    const int tid  = threadIdx.x;
    const int lane = tid & 63;
    const int wave = tid >> 6;
    const int h    = lane >> 5;
    const int r31  = lane & 31;

    const int bn = (blockIdx.x & 15) * BN;   // bn fastest -> A-panel L2/L3 reuse
    const int bm = (blockIdx.x >> 4) * BM;

    const int wm = (wave >> 1) * 64;
    const int wn = (wave & 1) * 128;

    const int P0 = (bm + wm) >> 5;           // A panel of tile i=0 (i adds 1)
    const int Q0 = ((bn + wn) >> 7) * 4;     // B panel of tile j=0 (j adds 1)

    const uint8_t* aBase = Apack + (size_t)P0 * 8 * 2048 + h * 1024 + r31 * 32;
    const uint8_t* bBase = Bpack + (size_t)Q0 * 8 * 2048 + h * 1024 + r31 * 32;

    f32x16 acc[2][4] = {};   // 128 VGPRs

    #pragma unroll
    for (int ks = 0; ks < 8; ++ks) {
        v8i av[2], bv[4];
        #pragma unroll
        for (int i = 0; i < 2; ++i) {
            const uint8_t* p = aBase + (size_t)(i * 8 + ks) * 2048;
            uint4 lo = *(const uint4*)(p);
            uint4 hi = *(const uint4*)(p + 16);
            av[i] = (v8i){(int)lo.x, (int)lo.y, (int)lo.z, (int)lo.w,
                          (int)hi.x, (int)hi.y, (int)hi.z, (int)hi.w};
        }
        #pragma unroll
        for (int j = 0; j < 4; ++j) {
            const uint8_t* p = bBase + (size_t)(j * 8 + ks) * 2048;
            uint4 lo = *(const uint4*)(p);
            uint4 hi = *(const uint4*)(p + 16);
            bv[j] = (v8i){(int)lo.x, (int)lo.y, (int)lo.z, (int)lo.w,
                          (int)hi.x, (int)hi.y, (int)hi.z, (int)hi.w};
        }
        #pragma unroll
        for (int i = 0; i < 2; ++i)
            #pragma unroll
            for (int j = 0; j < 4; ++j)
                acc[i][j] = __builtin_amdgcn_mfma_scale_f32_32x32x64_f8f6f4(
                    av[i], bv[j], acc[i][j],
                    0 /*fp8*/, 0 /*fp8*/,
                    0, 0x7F7F7F7Fu, 0, 0x7F7F7F7Fu);
    }

    // epilogue: out = exp(-(xsq - 2*cross + csq)), float4 stores (col interleave)
    // C/D 32x32: tile col = lane&31 -> global col bn + wn + 4*r31 + j
    const float4 cs4 = *(const float4*)(csq + bn + wn + 4 * r31);

    #pragma unroll
    for (int i = 0; i < 2; ++i) {
        #pragma unroll
        for (int r = 0; r < 16; ++r) {
            const int gm = bm + wm + 32 * i + 4 * h + (r & 3) + 8 * (r >> 2);
            const float xs = xsq[gm];
            float4 o;
            o.x = __expf(-(xs - 2.0f * acc[i][0][r] + cs4.x));
            o.y = __expf(-(xs - 2.0f * acc[i][1][r] + cs4.y));
            o.z = __expf(-(xs - 2.0f * acc[i][2][r] + cs4.z));
            o.w = __expf(-(xs - 2.0f * acc[i][3][r] + cs4.w));
            *(float4*)(out + (size_t)gm * N_DIM + bn + wn + 4 * r31) = o;
        }
    }
}

extern "C" void kernel_launch(void* const* d_in, const int* in_sizes, int n_in,
                              void* d_out, int out_size, void* d_ws, size_t ws_size,
                              hipStream_t stream) {
    const float* X = (const float*)d_in[0];
    const float* C = (const float*)d_in[1];
    float* out = (float*)d_out;

    uint8_t* Apack = (uint8_t*)d_ws;                          // 8 MB
    uint8_t* Bpack = Apack + (size_t)M_DIM * K_DIM;           // 2 MB
    float* xsq = (float*)(Bpack + (size_t)N_DIM * K_DIM);     // 64 KB
    float* csq = xsq + M_DIM;                                 // 16 KB

    convert_norm_kernel<<<(M_DIM + N_DIM) / 4, 256, 0, stream>>>(X, C, Apack, Bpack, xsq, csq);
    rbf_mfma_kernel<<<(M_DIM / BM) * (N_DIM / BN), 256, 0, stream>>>(Apack, Bpack, xsq, csq, out);
}

// Round 7
// 300.051 us; speedup vs baseline: 1.0551x; 1.0549x over previous
//
#include <hip/hip_runtime.h>
#include <stdint.h>

#define M_DIM 16384
#define N_DIM 4096
#define K_DIM 512

#define BM 128
#define BN 128
#define BK 128

typedef int v8i __attribute__((ext_vector_type(8)));
typedef float f32x16 __attribute__((ext_vector_type(16)));
typedef float f32x4v __attribute__((ext_vector_type(4)));

typedef __attribute__((address_space(3))) uint32_t lds_u32_t;
typedef const __attribute__((address_space(1))) uint32_t glob_u32_t;

__device__ __forceinline__ void gload16(const void* g, void* l) {
    __builtin_amdgcn_global_load_lds((glob_u32_t*)g, (lds_u32_t*)l, 16, 0, 0);
}

// one wave per row: fp32 row -> fp8 e4m3 row (8 B/lane) + fp32 sum of squares.
__global__ __launch_bounds__(256)
void convert_norm_kernel(const float* __restrict__ X, const float* __restrict__ C,
                         uint8_t* __restrict__ Xf8, uint8_t* __restrict__ Cf8,
                         float* __restrict__ xsq, float* __restrict__ csq) {
    const int wave = threadIdx.x >> 6;
    const int lane = threadIdx.x & 63;
    const int row = blockIdx.x * 4 + wave;
    const float* src;
    uint8_t* dst;
    float* nrm;
    int r;
    if (row < M_DIM) { src = X; dst = Xf8; nrm = xsq; r = row; }
    else             { src = C; dst = Cf8; nrm = csq; r = row - M_DIM; }

    const float4* p = (const float4*)(src + (size_t)r * K_DIM) + lane * 2;
    float4 a = p[0], b = p[1];
    uint32_t lo = 0, hi = 0;
    lo = __builtin_amdgcn_cvt_pk_fp8_f32(a.x, a.y, lo, false);
    lo = __builtin_amdgcn_cvt_pk_fp8_f32(a.z, a.w, lo, true);
    hi = __builtin_amdgcn_cvt_pk_fp8_f32(b.x, b.y, hi, false);
    hi = __builtin_amdgcn_cvt_pk_fp8_f32(b.z, b.w, hi, true);
    *(uint2*)(dst + (size_t)r * K_DIM + lane * 8) = make_uint2(lo, hi);

    float s = a.x*a.x + a.y*a.y + a.z*a.z + a.w*a.w
            + b.x*b.x + b.y*b.y + b.z*b.z + b.w*b.w;
    #pragma unroll
    for (int off = 32; off > 0; off >>= 1) s += __shfl_down(s, off, 64);
    if (lane == 0) nrm[r] = s;
}

// Block 128x128, 4 waves each 32x128 (1x4 of mfma_scale 32x32x64 fp8, acc=64 VGPR).
// Single-buffered LDS (32 KB) via global_load_lds w16, BK=128, 3-4 blocks/CU.
// LDS rows: 128 B = 8 chunks; chunk c of row r at slot (c+r)&7 -> conflict-free
// ds_read_b128 AND realizable by global_load_lds. k-chunk map identical on A and
// B -> dot product aligns (permutation-invariant).
// B LDS row p = j*32 + r  <->  global col bn + 4r + j  (column interleave), so
// lane r31 owns 4 consecutive output cols -> float4 nontemporal stores.
__global__ __launch_bounds__(256, 3)
void rbf_mfma_kernel(const uint8_t* __restrict__ A8, const uint8_t* __restrict__ B8,
                     const float* __restrict__ xsq, const float* __restrict__ csq,
                     float* __restrict__ out) {
    __shared__ uint8_t As[BM * BK];   // 16 KB
    __shared__ uint8_t Bs[BN * BK];   // 16 KB

    const int tid  = threadIdx.x;
    const int lane = tid & 63;
    const int wave = tid >> 6;
    const int h    = lane >> 5;
    const int r31  = lane & 31;

    const int bn = (blockIdx.x & 31) * BN;   // bn fastest -> A-slab L2 reuse
    const int bm = (blockIdx.x >> 5) * BM;

    // ---- staging map ----
    const int tr = tid >> 3;            // 0..31: row within 32-row round
    const int tc = tid & 7;             // dest chunk slot
    const int cc = (tc - tr) & 7;       // swizzled source chunk

    const uint8_t* gA = A8 + (size_t)(bm + tr) * K_DIM + cc * 16;
    // B col interleave: LDS row p=32R+tr <- global col bn + 4*tr + R
    const uint8_t* gB = B8 + (size_t)(bn + 4 * tr) * K_DIM + cc * 16;
    uint8_t* AsW = As + wave * 1024;
    uint8_t* BsW = Bs + wave * 1024;

    // ---- fragment-read constants ----
    const uint8_t* aRow = As + (32 * wave + r31) * BK;  // A rows = 32*wave + r31
    const uint8_t* bRow = Bs + r31 * BK;                // B tile j at +j*32 rows

    f32x16 acc[4] = {};   // 64 VGPRs

    for (int kk = 0; kk < 4; ++kk) {
        const int koff = kk * 128;
        #pragma unroll
        for (int R = 0; R < 4; ++R) {
            gload16(gA + koff + (size_t)R * 32 * K_DIM, AsW + R * 4096);
            gload16(gB + koff + (size_t)R * K_DIM, BsW + R * 4096);
        }
        __syncthreads();

        #pragma unroll
        for (int ksl = 0; ksl < 2; ++ksl) {
            const int c0 = ksl * 4 + 2 * h;
            const int s0 = ((c0 + 0 + r31) & 7) * 16;
            const int s1 = ((c0 + 1 + r31) & 7) * 16;
            v8i av, bv[4];
            {
                uint4 lo = *(const uint4*)(aRow + s0);
                uint4 hi = *(const uint4*)(aRow + s1);
                av = (v8i){(int)lo.x, (int)lo.y, (int)lo.z, (int)lo.w,
                           (int)hi.x, (int)hi.y, (int)hi.z, (int)hi.w};
            }
            #pragma unroll
            for (int j = 0; j < 4; ++j) {
                uint4 lo = *(const uint4*)(bRow + j * 32 * BK + s0);
                uint4 hi = *(const uint4*)(bRow + j * 32 * BK + s1);
                bv[j] = (v8i){(int)lo.x, (int)lo.y, (int)lo.z, (int)lo.w,
                              (int)hi.x, (int)hi.y, (int)hi.z, (int)hi.w};
            }
            #pragma unroll
            for (int j = 0; j < 4; ++j)
                acc[j] = __builtin_amdgcn_mfma_scale_f32_32x32x64_f8f6f4(
                    av, bv[j], acc[j],
                    0 /*fp8*/, 0 /*fp8*/,
                    0, 0x7F7F7F7Fu, 0, 0x7F7F7F7Fu);
        }
        __syncthreads();
    }

    // ---- epilogue: out = exp(-(xsq - 2*cross + csq)), float4 NT stores ----
    // C/D 32x32: tile col = lane&31 -> global col bn + 4*r31 + j (interleave)
    const float4 cs4 = *(const float4*)(csq + bn + 4 * r31);

    #pragma unroll
    for (int r = 0; r < 16; ++r) {
        const int gm = bm + 32 * wave + 4 * h + (r & 3) + 8 * (r >> 2);
        const float xs = xsq[gm];
        f32x4v o;
        o.x = __expf(-(xs - 2.0f * acc[0][r] + cs4.x));
        o.y = __expf(-(xs - 2.0f * acc[1][r] + cs4.y));
        o.z = __expf(-(xs - 2.0f * acc[2][r] + cs4.z));
        o.w = __expf(-(xs - 2.0f * acc[3][r] + cs4.w));
        __builtin_nontemporal_store(o, (f32x4v*)(out + (size_t)gm * N_DIM + bn + 4 * r31));
    }
}

extern "C" void kernel_launch(void* const* d_in, const int* in_sizes, int n_in,
                              void* d_out, int out_size, void* d_ws, size_t ws_size,
                              hipStream_t stream) {
    const float* X = (const float*)d_in[0];
    const float* C = (const float*)d_in[1];
    float* out = (float*)d_out;

    uint8_t* Xf8 = (uint8_t*)d_ws;                            // 8 MB
    uint8_t* Cf8 = Xf8 + (size_t)M_DIM * K_DIM;               // 2 MB
    float* xsq = (float*)(Cf8 + (size_t)N_DIM * K_DIM);       // 64 KB
    float* csq = xsq + M_DIM;                                 // 16 KB

    convert_norm_kernel<<<(M_DIM + N_DIM) / 4, 256, 0, stream>>>(X, C, Xf8, Cf8, xsq, csq);
    rbf_mfma_kernel<<<(M_DIM / BM) * (N_DIM / BN), 256, 0, stream>>>(Xf8, Cf8, xsq, csq, out);
}